// Round 15
// baseline (79.917 us; speedup 1.0000x reference)
//
#include <hip/hip_runtime.h>
#include <hip/hip_bf16.h>

// ILA layer (fp32 I/O): key = W@ft, query = W@fk (1x1 conv, shared W),
// sim[p,k] = <query[p], key[neighbor_k(p)]> over 9x9 window (zero-padded keys),
// weight = softmax_k(sim)  (OOB entries participate with sim=0),
// out[c,p] = sum_k weight[k] * ft[c, neighbor_k(p)]  (zero-padded ft).
// n=2, c=128, h=w=64, L=9 (81 neighbors).
// K/Q/ft intermediates fp16. proj = MFMA GEMM; sim dots = MFMA banded QK^T.
// R15: w packed p-major (simb_p[p][152], slot r*16+dx); ftl XOR-swizzled stride-128;
// proj x-staging via 4c x 4px register transpose (vector LDS writes).

#define Hh 64
#define Ww 64
#define Cc 128
#define Nn 2
#define KK 81
#define HW (Hh * Ww)          // 4096
#define CHW (Cc * HW)         // 524288
#define P_TOT (Nn * HW)       // 8192

typedef _Float16 h8 __attribute__((ext_vector_type(8)));
typedef _Float16 h4 __attribute__((ext_vector_type(4)));
typedef float f4v __attribute__((ext_vector_type(4)));

// ---------------- Kernel A: projection via MFMA.
__global__ __launch_bounds__(256) void proj_kernel(const float* __restrict__ ft,
                                                   const float* __restrict__ fk,
                                                   const float* __restrict__ Wm,
                                                   _Float16* __restrict__ Qbuf,
                                                   _Float16* __restrict__ Kbuf,
                                                   _Float16* __restrict__ fth) {
    __shared__ __align__(16) _Float16 Wth[128 * 136];  // [o][i] fp16 (== B[k][n] view)
    __shared__ __align__(16) _Float16 xkh[32 * 136];   // [px][c] fp16
    __shared__ __align__(16) _Float16 xqh[32 * 136];
    const int t = threadIdx.x;
    const int p0 = blockIdx.x * 32;       // 4096 % 32 == 0: never crosses n
    const int nn = p0 >> 12;
    const int gbase = nn * CHW + (p0 & 4095);

#pragma unroll 4
    for (int e = t; e < 4096; e += 256) {             // stage W -> fp16
        const int n = e >> 5, ch = e & 31;
        const float4 v = *(const float4*)&Wm[n * 128 + (ch << 2)];
        h4 hv; hv[0] = (_Float16)v.x; hv[1] = (_Float16)v.y;
               hv[2] = (_Float16)v.z; hv[3] = (_Float16)v.w;
        *(h4*)&Wth[n * 136 + (ch << 2)] = hv;
    }
    {   // stage x -> fp16 px-major via 4c x 4px register transpose (1 tile/thread)
        const int pc = t & 7, cg = t >> 3;            // 8 px-groups x 32 c-groups
        const int c0 = cg << 2, px0 = pc << 2;
        float4 vk[4], vq[4];
#pragma unroll
        for (int j = 0; j < 4; ++j) {
            vk[j] = *(const float4*)&ft[gbase + (c0 + j) * HW + px0];
            vq[j] = *(const float4*)&fk[gbase + (c0 + j) * HW + px0];
        }
#pragma unroll
        for (int pp = 0; pp < 4; ++pp) {
            h4 hk, hq;
#pragma unroll
            for (int j = 0; j < 4; ++j) {
                hk[j] = (_Float16)((const float*)&vk[j])[pp];
                hq[j] = (_Float16)((const float*)&vq[j])[pp];
            }
            *(h4*)&xkh[(px0 + pp) * 136 + c0] = hk;
            *(h4*)&xqh[(px0 + pp) * 136 + c0] = hq;
        }
    }
    __syncthreads();

#pragma unroll
    for (int e = t; e < 512; e += 256) {              // fth: coalesced h8 copies
        const int px = e >> 4, cq = e & 15;
        *(h8*)&fth[(size_t)(p0 + px) * 128 + (cq << 3)] =
            *(const h8*)&xkh[px * 136 + (cq << 3)];
    }

    const int lane = t & 63, wv = t >> 6;
    const int quad = lane >> 4, l15 = lane & 15;
    const _Float16* xs = (wv >> 1) ? xqh : xkh;
    _Float16* dst = (wv >> 1) ? Qbuf : Kbuf;
    const int mt = wv & 1;
    const int abase = (mt * 16 + l15) * 136 + (quad << 3);
    const h8 a0 = *(const h8*)&xs[abase];
    const h8 a1 = *(const h8*)&xs[abase + 32];
    const h8 a2 = *(const h8*)&xs[abase + 64];
    const h8 a3 = *(const h8*)&xs[abase + 96];
#pragma unroll
    for (int nt = 0; nt < 8; ++nt) {
        const int bbase = (nt * 16 + l15) * 136 + (quad << 3);
        const h8 b0 = *(const h8*)&Wth[bbase];
        const h8 b1 = *(const h8*)&Wth[bbase + 32];
        const h8 b2 = *(const h8*)&Wth[bbase + 64];
        const h8 b3 = *(const h8*)&Wth[bbase + 96];
        f4v acc = {0.f, 0.f, 0.f, 0.f};
        acc = __builtin_amdgcn_mfma_f32_16x16x32_f16(a0, b0, acc, 0, 0, 0);
        acc = __builtin_amdgcn_mfma_f32_16x16x32_f16(a1, b1, acc, 0, 0, 0);
        acc = __builtin_amdgcn_mfma_f32_16x16x32_f16(a2, b2, acc, 0, 0, 0);
        acc = __builtin_amdgcn_mfma_f32_16x16x32_f16(a3, b3, acc, 0, 0, 0);
        const int col = nt * 16 + l15;
        const size_t rb = (size_t)(p0 + mt * 16 + (quad << 2)) * 128 + col;
#pragma unroll
        for (int r = 0; r < 4; ++r)
            dst[rb + (size_t)r * 128] = (_Float16)acc[r];
    }
}

// ---------------- Kernel B (fused): MFMA dots + softmax + weighting. 8-px row strip.
__global__ __launch_bounds__(256, 4) void sim_weight_kernel(const _Float16* __restrict__ Qbuf,
                                                            const _Float16* __restrict__ Kbuf,
                                                            const _Float16* __restrict__ fth,
                                                            float* __restrict__ out) {
    __shared__ __align__(16) unsigned char smem[39552];
    _Float16* Ksw  = (_Float16*)smem;             // 18432 halves [0, 36864)
    _Float16* Qsw  = (_Float16*)(smem + 36864);   // 1024 halves  [36864, 38912); dead after dots
    _Float16* ftl  = (_Float16*)smem;             // XOR-swizzled [v][128], [0,36864) — aliases Ksw
    float*    simbF= (float*)smem;                // [k][8] fp32, 2592 B — alive B2a..B2c only
    _Float16* simb_p=(_Float16*)(smem + 36864);   // [p][152] halves, 2432 B — aliases Qsw after B2a
    float*    redM = (float*)(smem + 39296);      // 32 floats
    float*    redS = (float*)(smem + 39424);      // 32 floats

    const int t  = threadIdx.x;
    const int b  = blockIdx.x;
    const int x0 = (b & 7) << 3;
    const int y  = (b >> 3) & 63;
    const int nn = b >> 9;
    const int pg0 = (nn << 12) + (y << 6) + x0;

    // ---- stage K: zero-padded 9x16 window, h8 copies, XOR-swizzled slots
#pragma unroll 3
    for (int e = t; e < 144 * 16; e += 256) {
        const int v = e >> 4, ci = e & 15;
        const int gx = x0 + (v & 15) - 4;
        const int gy = y + (v >> 4) - 4;
        h8 val = {0, 0, 0, 0, 0, 0, 0, 0};
        if ((unsigned)gx < 64u && (unsigned)gy < 64u)
            val = *(const h8*)&Kbuf[(size_t)((nn << 12) + (gy << 6) + gx) * 128 + (ci << 3)];
        *(h8*)&Ksw[(v << 7) + ((ci ^ (v & 15)) << 3)] = val;
    }
    if (t < 128) {   // stage Q: 8 vectors x 16 chunks
        const int v = t >> 4, ci = t & 15;
        *(h8*)&Qsw[(v << 7) + ((ci ^ v) << 3)] =
            *(const h8*)&Qbuf[(size_t)(pg0 + v) * 128 + (ci << 3)];
    }
    __syncthreads();   // B1

    // ---- dots via MFMA: per r, S_r[xx][p] = sum_c Ksw[r*16+xx][c] * Q[p][c]
    const int lane = t & 63, wv = t >> 6;
    const int quad = lane >> 4, l15 = lane & 15;
    const int qrow = l15 & 7;                 // clamp: cols 8-15 duplicate, never extracted
    h8 qb[4];
#pragma unroll
    for (int kc = 0; kc < 4; ++kc) {
        const int ci = (kc << 2) + quad;
        qb[kc] = *(const h8*)&Qsw[(qrow << 7) + ((ci ^ qrow) << 3)];
    }
    const int r0 = wv, r1 = wv + 4;           // r2 = 8 computed by all, extracted by wave 0
    f4v acc0 = {0.f,0.f,0.f,0.f}, acc1 = acc0, acc2 = acc0;
#pragma unroll
    for (int kc = 0; kc < 4; ++kc) {
        const int ci = (kc << 2) + quad;
        const h8 kA = *(const h8*)&Ksw[(((r0 << 4) + l15) << 7) + ((ci ^ l15) << 3)];
        const h8 kB = *(const h8*)&Ksw[(((r1 << 4) + l15) << 7) + ((ci ^ l15) << 3)];
        const h8 kC = *(const h8*)&Ksw[(((8  << 4) + l15) << 7) + ((ci ^ l15) << 3)];
        acc0 = __builtin_amdgcn_mfma_f32_16x16x32_f16(kA, qb[kc], acc0, 0, 0, 0);
        acc1 = __builtin_amdgcn_mfma_f32_16x16x32_f16(kB, qb[kc], acc1, 0, 0, 0);
        acc2 = __builtin_amdgcn_mfma_f32_16x16x32_f16(kC, qb[kc], acc2, 0, 0, 0);
    }
    __syncthreads();   // B2a: MFMA reads done; Ksw/Qsw dead

    // extraction: valid iff p=l15<8 and dx=xx-p in [0,9); k = r*9+dx
#pragma unroll
    for (int reg = 0; reg < 4; ++reg) {
        const int xx = (quad << 2) + reg;
        const int dx = xx - l15;
        const bool ok = (l15 < 8) && (dx >= 0) && (dx < 9);
        if (ok)            simbF[(r0 * 9 + dx) * 8 + l15] = acc0[reg];
        if (ok)            simbF[(r1 * 9 + dx) * 8 + l15] = acc1[reg];
        if (ok && wv == 0) simbF[(8  * 9 + dx) * 8 + l15] = acc2[reg];
    }
    __syncthreads();   // B2b: simbF complete

    const int p = t & 7, kb = t >> 3;
    const bool has2 = (kb + 64 < KK);
    const float s0 = simbF[kb * 8 + p];
    const float s1 = simbF[(kb + 32) * 8 + p];
    const float s2 = has2 ? simbF[(kb + 64) * 8 + p] : 0.f;
    __syncthreads();   // B2c: readback done; ftl may overwrite [0, 36864)

    // ---- restage ft: h8 copies fth[pixel] -> ftl, XOR-swizzled (same form as Ksw)
#pragma unroll 3
    for (int e = t; e < 144 * 16; e += 256) {
        const int v = e >> 4, ci = e & 15;
        const int gx = x0 + (v & 15) - 4;
        const int gy = y + (v >> 4) - 4;
        h8 val = {0, 0, 0, 0, 0, 0, 0, 0};
        if ((unsigned)gx < 64u && (unsigned)gy < 64u)
            val = *(const h8*)&fth[(size_t)((nn << 12) + (gy << 6) + gx) * 128 + (ci << 3)];
        *(h8*)&ftl[(v << 7) + ((ci ^ (v & 15)) << 3)] = val;
    }

    // ---- softmax in registers: reduce over lanes sharing p (bits 3..5 of lane id)
    float m = fmaxf(s0, s1);
    if (has2) m = fmaxf(m, s2);
#pragma unroll
    for (int off = 8; off <= 32; off <<= 1) m = fmaxf(m, __shfl_xor(m, off));
    if ((t & 56) == 0) redM[((t >> 6) << 3) + p] = m;   // one lane per (wave, p)
    __syncthreads();   // B3 (also covers ftl writes)
    float mm = fmaxf(fmaxf(redM[p], redM[8 + p]), fmaxf(redM[16 + p], redM[24 + p]));
    const float e0 = __expf(s0 - mm);
    const float e1 = __expf(s1 - mm);
    const float e2 = has2 ? __expf(s2 - mm) : 0.f;
    // w packed p-major, slot r*16+dx (keeps h8 reads aligned, extraction compile-time)
    {
        const int k1 = kb + 32, k2 = kb + 64;
        simb_p[p * 152 + (kb / 9) * 16 + (kb % 9)] = (_Float16)e0;
        simb_p[p * 152 + (k1 / 9) * 16 + (k1 % 9)] = (_Float16)e1;
        if (has2) simb_p[p * 152 + (k2 / 9) * 16 + (k2 % 9)] = (_Float16)e2;
    }
    float s = e0 + e1 + e2;
#pragma unroll
    for (int off = 8; off <= 32; off <<= 1) s += __shfl_xor(s, off);
    if ((t & 56) == 0) redS[((t >> 6) << 3) + p] = s;
    __syncthreads();   // B4
    const float inv = 1.f / (redS[p] + redS[8 + p] + redS[16 + p] + redS[24 + p]);

    // ---- weighting: thread = (p, cq); 4 channels per thread.
    // w: 1 b128 + 1 u16 per r (was 9 u16); f: h4 from XOR-swizzled ftl.
    const int cq = t >> 3;
    const int ci = cq >> 1, sub = (cq & 1) << 2;
    const int pb = p * 152;
    float4 acc = make_float4(0, 0, 0, 0);
    for (int r = 0; r < 9; ++r) {
        const h8 wA = *(const h8*)&simb_p[pb + (r << 4)];
        const float w8 = (float)simb_p[pb + (r << 4) + 8];
        const int vb = (r << 4) + p;              // v = vb + dx; v&15 == p+dx (<=15)
#pragma unroll
        for (int dx = 0; dx < 9; ++dx) {
            const float w = (dx < 8) ? (float)wA[dx] : w8;
            const int v = vb + dx;
            const h4 f = *(const h4*)&ftl[(v << 7) + ((ci ^ (p + dx)) << 3) + sub];
            acc.x += (float)f[0] * w;
            acc.y += (float)f[1] * w;
            acc.z += (float)f[2] * w;
            acc.w += (float)f[3] * w;
        }
    }
    const size_t ob = (size_t)((nn * Cc + (cq << 2)) << 12) + (y << 6) + x0 + p;
    out[ob]          = acc.x * inv;
    out[ob + HW]     = acc.y * inv;
    out[ob + 2*HW]   = acc.z * inv;
    out[ob + 3*HW]   = acc.w * inv;
}

extern "C" void kernel_launch(void* const* d_in, const int* in_sizes, int n_in,
                              void* d_out, int out_size, void* d_ws, size_t ws_size,
                              hipStream_t stream) {
    const float* ft = (const float*)d_in[0];
    const float* fk = (const float*)d_in[1];
    const float* Wm = (const float*)d_in[2];
    float* out = (float*)d_out;

    _Float16* wsh  = (_Float16*)d_ws;    // 6 MB: Qh(2MB) + Kh(2MB) + fth(2MB)
    _Float16* Qbuf = wsh;                // [p][c]  8192*128 halves
    _Float16* Kbuf = wsh + 1048576;      // [p][c]  8192*128 halves
    _Float16* fth  = wsh + 2097152;      // fp16 ft, PIXEL-MAJOR [p][c]

    proj_kernel<<<256, 256, 0, stream>>>(ft, fk, Wm, Qbuf, Kbuf, fth);
    sim_weight_kernel<<<1024, 256, 0, stream>>>(Qbuf, Kbuf, fth, out);
}